// Round 14
// baseline (496.746 us; speedup 1.0000x reference)
//
#include <hip/hip_runtime.h>
#include <stdint.h>

#define N_NODES 50000
#define N_EDGES 800000
#define N_PAD   50176    // 98 * 512, K-padding for MFMA pool
#define FEAT    128
#define NGRAPH  64
#define PCHUNK  512
#define NCHUNKS (N_PAD / PCHUNK)   // 98
#define NBUCKET 196      // dst>>8 buckets

typedef __attribute__((ext_vector_type(8))) short short8;
typedef __attribute__((ext_vector_type(4))) float floatx4;

static __device__ __forceinline__ ushort f2bf(float f) {
  uint32_t x = __float_as_uint(f);
  x += 0x7FFF + ((x >> 16) & 1);   // RNE
  return (ushort)(x >> 16);
}
static __device__ __forceinline__ float bfLo(uint32_t u) {
  return __uint_as_float(u << 16);
}
static __device__ __forceinline__ float bfHi(uint32_t u) {
  return __uint_as_float(u & 0xFFFF0000u);
}

// ---------------- fp32 -> bf16 row-major ---------------------------------
__global__ __launch_bounds__(256) void cvt_bf16(const float* __restrict__ in,
                                                ushort* __restrict__ out, int n4) {
  int i = blockIdx.x * 256 + threadIdx.x;
  if (i >= n4) return;
  float4 v = ((const float4*)in)[i];
  ushort4 u;
  u.x = f2bf(v.x); u.y = f2bf(v.y); u.z = f2bf(v.z); u.w = f2bf(v.w);
  ((ushort4*)out)[i] = u;
}

// ---------------- degree count -------------------------------------------
__global__ __launch_bounds__(256) void count_deg(const int* __restrict__ dst,
                                                 int* __restrict__ cnt) {
  int e = blockIdx.x * 256 + threadIdx.x;
  if (e < N_EDGES) atomicAdd(&cnt[dst[e]], 1);
}

// dinv + coef self-term + per-graph node counts (LDS binned)
__global__ __launch_bounds__(256) void compute_dinv(const int* __restrict__ cnt,
                                                    const int* __restrict__ batch,
                                                    float* __restrict__ dinv,
                                                    float* __restrict__ coefT,
                                                    float* __restrict__ cnt_g) {
  __shared__ int bins[NGRAPH];
  if (threadIdx.x < NGRAPH) bins[threadIdx.x] = 0;
  __syncthreads();
  int i = blockIdx.x * 256 + threadIdx.x;
  if (i < N_NODES) {
    float di = rsqrtf((float)cnt[i] + 1.0f);
    dinv[i] = di;
    int g = batch[i];
    coefT[(size_t)g * N_PAD + i] = di * di;   // coalesced (batch sorted)
    atomicAdd(&bins[g], 1);
  }
  __syncthreads();
  if (threadIdx.x < NGRAPH && bins[threadIdx.x] > 0)
    atomicAdd(&cnt_g[threadIdx.x], (float)bins[threadIdx.x]);
}

// ---------------- exclusive scan (3 kernels) -----------------------------
__global__ __launch_bounds__(256) void scan1(const int* __restrict__ cnt,
                                             int* __restrict__ ptr,
                                             int* __restrict__ bsums) {
  __shared__ int tmp[256];
  int i = blockIdx.x * 256 + threadIdx.x;
  int v = (i < N_NODES) ? cnt[i] : 0;
  tmp[threadIdx.x] = v;
  __syncthreads();
  for (int off = 1; off < 256; off <<= 1) {
    int t = (threadIdx.x >= off) ? tmp[threadIdx.x - off] : 0;
    __syncthreads();
    tmp[threadIdx.x] += t;
    __syncthreads();
  }
  if (i < N_NODES) ptr[i] = tmp[threadIdx.x] - v;           // exclusive
  if (threadIdx.x == 255) bsums[blockIdx.x] = tmp[255];
}

__global__ __launch_bounds__(256) void scan2(int* __restrict__ bsums, int nb) {
  __shared__ int tmp[256];
  int v = (threadIdx.x < nb) ? bsums[threadIdx.x] : 0;
  tmp[threadIdx.x] = v;
  __syncthreads();
  for (int off = 1; off < 256; off <<= 1) {
    int t = (threadIdx.x >= off) ? tmp[threadIdx.x - off] : 0;
    __syncthreads();
    tmp[threadIdx.x] += t;
    __syncthreads();
  }
  if (threadIdx.x < nb) bsums[threadIdx.x] = tmp[threadIdx.x] - v;  // exclusive
}

// also initializes bucket cursors (64B-padded): bucket b starts at csr_ptr[256b]
__global__ __launch_bounds__(256) void scan3(int* __restrict__ ptr,
                                             int* __restrict__ cursor,
                                             const int* __restrict__ bsums,
                                             int* __restrict__ bcur) {
  int i = blockIdx.x * 256 + threadIdx.x;
  if (i < N_NODES) {
    int p = ptr[i] + bsums[blockIdx.x];
    ptr[i] = p;
    cursor[i] = p;
    if ((i & 255) == 0) bcur[(i >> 8) * 16] = p;   // stride-16 ints = 64B pad
  }
}

// ---------------- stage A: scatter edges to bucket-major temp ------------
// Writes advance 196 sequential frontiers (line-local) instead of 800k
// random lines. s,d < 2^16 -> packed in one dword + nrm.
__global__ __launch_bounds__(256) void scatter_bucket(const int* __restrict__ src,
                                                      const int* __restrict__ dst,
                                                      const float* __restrict__ dinv,
                                                      int* __restrict__ bcur,
                                                      int2* __restrict__ tmp) {
  int e = blockIdx.x * 256 + threadIdx.x;
  if (e >= N_EDGES) return;
  int s = src[e], d = dst[e];
  int pos = atomicAdd(&bcur[(d >> 8) * 16], 1);
  float nrm = dinv[s] * dinv[d];
  tmp[pos] = make_int2(s | (d << 16), __float_as_int(nrm));
}

// ---------------- stage B: exact CSR placement + coef atomics ------------
// Reads bucket-major (coalesced); writes land in a ~32KB L2-resident CSR
// window; coefT atomic row (batch[d]) is near-constant per bucket.
__global__ __launch_bounds__(256) void csr_scatter(const int2* __restrict__ tmp,
                                                   const int* __restrict__ batch,
                                                   int* __restrict__ cursor,
                                                   int2* __restrict__ edges,
                                                   float* __restrict__ coefT) {
  int i = blockIdx.x * 256 + threadIdx.x;
  if (i >= N_EDGES) return;
  int2 rec = tmp[i];
  int s = rec.x & 0xFFFF;
  int d = (rec.x >> 16) & 0xFFFF;
  int pos = atomicAdd(&cursor[d], 1);
  edges[pos] = make_int2(s, rec.y);
  atomicAdd(&coefT[(size_t)batch[d] * N_PAD + s], __int_as_float(rec.y));
}

// ---------------- GEMM [M,128] x [128,128] via MFMA bf16, bf16 out -------
__global__ __launch_bounds__(256) void gemm128(const ushort* __restrict__ X,
                                               const ushort* __restrict__ W,
                                               ushort* __restrict__ XW,
                                               int nTilesM) {
  int wave = (blockIdx.x * 256 + threadIdx.x) >> 6;
  int lane = threadIdx.x & 63;
  int mt = wave >> 3;  // 8 n-tiles per m-tile
  int nt = wave & 7;
  if (mt >= nTilesM) return;
  int m0 = mt * 16, n0 = nt * 16;
  int r = lane & 15, quad = lane >> 4;
  floatx4 acc = {0.f, 0.f, 0.f, 0.f};
  const ushort* xrow = X + (size_t)(m0 + r) * FEAT;
#pragma unroll
  for (int kb = 0; kb < 4; ++kb) {
    int k0 = kb * 32 + quad * 8;
    short8 a = *(const short8*)(xrow + k0);
    short8 b;
#pragma unroll
    for (int j = 0; j < 8; ++j) b[j] = (short)W[(size_t)(k0 + j) * FEAT + n0 + r];
    acc = __builtin_amdgcn_mfma_f32_16x16x32_bf16(a, b, acc, 0, 0, 0);
  }
#pragma unroll
  for (int reg = 0; reg < 4; ++reg) {
    int row = quad * 4 + reg;
    XW[(size_t)(m0 + row) * FEAT + n0 + r] = f2bf(acc[reg]);
  }
}

// ---------------- aggregation (r6 proven): wave/node, 8-edge ILP ---------
__global__ __launch_bounds__(256) void agg_kernel(const ushort* __restrict__ msg,
                                                  const float* __restrict__ dinv,
                                                  const int* __restrict__ ptr,
                                                  const int* __restrict__ cnt,
                                                  const int2* __restrict__ edges,
                                                  const float* __restrict__ bias,
                                                  ushort* __restrict__ Hout) {
  int wave = (blockIdx.x * 256 + threadIdx.x) >> 6;
  int lane = threadIdx.x & 63;
  if (wave >= N_NODES) return;
  int v = wave;
  float di = dinv[v];
  const uint32_t* m32 = (const uint32_t*)msg;   // 64 dwords per node row
  uint32_t su = m32[(size_t)v * 64 + lane];
  float sn = di * di;
  float ax0 = bfLo(su) * sn, ay0 = bfHi(su) * sn;
  float ax1 = 0.f, ay1 = 0.f, ax2 = 0.f, ay2 = 0.f, ax3 = 0.f, ay3 = 0.f;
  int start = ptr[v];
  int n = cnt[v];
  int i = 0;
  if ((start & 1) && n > 0) {
    int2 e = edges[start];
    uint32_t u = m32[(size_t)e.x * 64 + lane];
    float nrm = __int_as_float(e.y);
    ax0 = fmaf(nrm, bfLo(u), ax0);
    ay0 = fmaf(nrm, bfHi(u), ay0);
    i = 1;
  }
  for (; i + 8 <= n; i += 8) {
    const int4* ep = (const int4*)(edges + start + i);   // 16B-aligned
    int4 q0 = ep[0], q1 = ep[1], q2 = ep[2], q3 = ep[3];
    uint32_t u0 = m32[(size_t)q0.x * 64 + lane];
    uint32_t u1 = m32[(size_t)q0.z * 64 + lane];
    uint32_t u2 = m32[(size_t)q1.x * 64 + lane];
    uint32_t u3 = m32[(size_t)q1.z * 64 + lane];
    uint32_t u4 = m32[(size_t)q2.x * 64 + lane];
    uint32_t u5 = m32[(size_t)q2.z * 64 + lane];
    uint32_t u6 = m32[(size_t)q3.x * 64 + lane];
    uint32_t u7 = m32[(size_t)q3.z * 64 + lane];
    float n0 = __int_as_float(q0.y), n1 = __int_as_float(q0.w);
    float n2 = __int_as_float(q1.y), n3 = __int_as_float(q1.w);
    float n4 = __int_as_float(q2.y), n5 = __int_as_float(q2.w);
    float n6 = __int_as_float(q3.y), n7 = __int_as_float(q3.w);
    ax0 = fmaf(n0, bfLo(u0), ax0); ay0 = fmaf(n0, bfHi(u0), ay0);
    ax1 = fmaf(n1, bfLo(u1), ax1); ay1 = fmaf(n1, bfHi(u1), ay1);
    ax2 = fmaf(n2, bfLo(u2), ax2); ay2 = fmaf(n2, bfHi(u2), ay2);
    ax3 = fmaf(n3, bfLo(u3), ax3); ay3 = fmaf(n3, bfHi(u3), ay3);
    ax0 = fmaf(n4, bfLo(u4), ax0); ay0 = fmaf(n4, bfHi(u4), ay0);
    ax1 = fmaf(n5, bfLo(u5), ax1); ay1 = fmaf(n5, bfHi(u5), ay1);
    ax2 = fmaf(n6, bfLo(u6), ax2); ay2 = fmaf(n6, bfHi(u6), ay2);
    ax3 = fmaf(n7, bfLo(u7), ax3); ay3 = fmaf(n7, bfHi(u7), ay3);
  }
  for (; i < n; ++i) {
    int2 e = edges[start + i];
    float nrm = __int_as_float(e.y);
    uint32_t u = m32[(size_t)e.x * 64 + lane];
    ax0 = fmaf(nrm, bfLo(u), ax0);
    ay0 = fmaf(nrm, bfHi(u), ay0);
  }
  float ax = (ax0 + ax1) + (ax2 + ax3) + bias[2 * lane];
  float ay = (ay0 + ay1) + (ay2 + ay3) + bias[2 * lane + 1];
  ax = fmaxf(ax, 0.f);
  ay = fmaxf(ay, 0.f);
  ushort2 h2;
  h2.x = f2bf(ax);
  h2.y = f2bf(ay);
  ((ushort2*)Hout)[(size_t)v * 64 + lane] = h2;
}

// ---------------- pool v4: P = coefT x h2 via MFMA (in-reg bf16 cvt) -----
__global__ __launch_bounds__(256) void pool_mfma(const ushort* __restrict__ h2,
                                                 const float* __restrict__ coefT,
                                                 float* __restrict__ P) {
  int wave = (blockIdx.x * 256 + threadIdx.x) >> 6;
  int lane = threadIdx.x & 63;
  int mt = wave & 3;
  int nt = (wave >> 2) & 7;
  int ck = wave >> 5;
  if (ck >= NCHUNKS) return;
  int c0 = ck * PCHUNK;
  int m0 = mt * 16, n0 = nt * 16;
  int r = lane & 15, quad = lane >> 4;
  floatx4 acc = {0.f, 0.f, 0.f, 0.f};
  const float* arow = coefT + (size_t)(m0 + r) * N_PAD + c0;
#pragma unroll 4
  for (int kb = 0; kb < 16; ++kb) {
    int k0 = kb * 32 + quad * 8;
    float4 af0 = *(const float4*)(arow + k0);
    float4 af1 = *(const float4*)(arow + k0 + 4);
    short8 a;
    a[0] = (short)f2bf(af0.x); a[1] = (short)f2bf(af0.y);
    a[2] = (short)f2bf(af0.z); a[3] = (short)f2bf(af0.w);
    a[4] = (short)f2bf(af1.x); a[5] = (short)f2bf(af1.y);
    a[6] = (short)f2bf(af1.z); a[7] = (short)f2bf(af1.w);
    short8 b;
#pragma unroll
    for (int j = 0; j < 8; ++j)
      b[j] = (short)h2[(size_t)(c0 + k0 + j) * FEAT + n0 + r];
    acc = __builtin_amdgcn_mfma_f32_16x16x32_bf16(a, b, acc, 0, 0, 0);
  }
#pragma unroll
  for (int reg = 0; reg < 4; ++reg) {
    int row = quad * 4 + reg;                    // graph within m-tile
    atomicAdd(&P[(size_t)(m0 + row) * FEAT + n0 + r], acc[reg]);
  }
}

// ---------------- fused head: Pn = P/cnt; f = Pn*W3+b3; fc1..fc5 ---------
__device__ __forceinline__ void head_layer(const float* __restrict__ IN,
                                           float* __restrict__ OUT,
                                           const float* __restrict__ w,
                                           const float* __restrict__ b,
                                           int K, int C, int Cp, int relu,
                                           float* __restrict__ gout, int t) {
  int parts = 1024 / Cp;
  int part = t / Cp;
  int c = t - part * Cp;
  int kchunk = K / parts;
  if (t < C) OUT[t] = b[t];
  __syncthreads();
  if (c < C) {
    int k0 = part * kchunk;
    float a0 = 0.f, a1 = 0.f, a2 = 0.f, a3 = 0.f;
    const float* wp = w + (size_t)k0 * C + c;
    if ((kchunk & 3) == 0) {
#pragma unroll 4
      for (int k = 0; k < kchunk; k += 4) {
        a0 = fmaf(IN[k0 + k],     wp[(size_t)k * C],       a0);
        a1 = fmaf(IN[k0 + k + 1], wp[(size_t)(k + 1) * C], a1);
        a2 = fmaf(IN[k0 + k + 2], wp[(size_t)(k + 2) * C], a2);
        a3 = fmaf(IN[k0 + k + 3], wp[(size_t)(k + 3) * C], a3);
      }
    } else {
      for (int k = 0; k < kchunk; ++k)
        a0 = fmaf(IN[k0 + k], wp[(size_t)k * C], a0);
    }
    atomicAdd(&OUT[c], (a0 + a1) + (a2 + a3));
  }
  __syncthreads();
  if (t < C) {
    float v = OUT[t];
    if (relu) { v = fmaxf(v, 0.f); OUT[t] = v; }
    if (gout) gout[t] = v;
  }
  __syncthreads();
}

__global__ __launch_bounds__(1024) void fc_head(const float* __restrict__ P,
                                                const float* __restrict__ cnt_g,
                                                const float* __restrict__ w3,
                                                const float* __restrict__ b3,
                                                const float* __restrict__ w1,
                                                const float* __restrict__ b1,
                                                const float* __restrict__ w2,
                                                const float* __restrict__ b2,
                                                const float* __restrict__ wf3,
                                                const float* __restrict__ bf3,
                                                const float* __restrict__ w4,
                                                const float* __restrict__ b4,
                                                const float* __restrict__ w5,
                                                const float* __restrict__ b5,
                                                float* __restrict__ out_f,
                                                float* __restrict__ out_y) {
  __shared__ float A[1024];
  __shared__ float B[1024];
  int r = blockIdx.x, t = threadIdx.x;
  if (t < FEAT) A[t] = P[r * FEAT + t] / fmaxf(cnt_g[r], 1.0f);   // Pn
  __syncthreads();
  head_layer(A, B, w3, b3, 128, 128, 128, 0, out_f + (size_t)r * FEAT, t);
  head_layer(B, A, w1, b1, 128, 1024, 1024, 1, nullptr, t);
  head_layer(A, B, w2, b2, 1024, 512, 512, 1, nullptr, t);
  head_layer(B, A, wf3, bf3, 512, 256, 256, 1, nullptr, t);
  head_layer(A, B, w4, b4, 256, 128, 128, 1, nullptr, t);
  head_layer(B, A, w5, b5, 128, 10, 16, 0, out_y + (size_t)r * 10, t);
}

// =========================================================================
extern "C" void kernel_launch(void* const* d_in, const int* in_sizes, int n_in,
                              void* d_out, int out_size, void* d_ws, size_t ws_size,
                              hipStream_t stream) {
  const float* x         = (const float*)d_in[0];
  const int*   ei        = (const int*)d_in[1];     // [2][E]: row0 src, row1 dst
  const int*   batch     = (const int*)d_in[2];
  const float* conv_w[3] = {(const float*)d_in[3], (const float*)d_in[5], (const float*)d_in[7]};
  const float* conv_b[3] = {(const float*)d_in[4], (const float*)d_in[6], (const float*)d_in[8]};
  const float* fc_w[5]   = {(const float*)d_in[9],  (const float*)d_in[11],
                            (const float*)d_in[13], (const float*)d_in[15],
                            (const float*)d_in[17]};
  const float* fc_b[5]   = {(const float*)d_in[10], (const float*)d_in[12],
                            (const float*)d_in[14], (const float*)d_in[16],
                            (const float*)d_in[18]};
  const int* e_src = ei;
  const int* e_dst = ei + N_EDGES;
  float* out_f = (float*)d_out;                  // [64][128] fp32  (output 0)
  float* out_y = (float*)d_out + NGRAPH * FEAT;  // [64][10]  fp32  (output 1)

  char* p = (char*)d_ws;
  auto carve = [&](size_t bytes) {
    char* r = p;
    p += (bytes + 255) & ~(size_t)255;
    return r;
  };
  int*    cnt_i   = (int*)carve(N_NODES * 4);
  float*  dinv    = (float*)carve(N_NODES * 4);
  int*    csr_ptr = (int*)carve(N_NODES * 4);
  int*    cursor  = (int*)carve(N_NODES * 4);
  int*    bsums   = (int*)carve(256 * 4);
  int*    bcur    = (int*)carve(NBUCKET * 16 * 4);                // 64B-padded cursors
  int2*   tmp     = (int2*)carve((size_t)N_EDGES * 8);            // bucket-major temp
  int2*   edges   = (int2*)carve((size_t)N_EDGES * 8);
  ushort* xb      = (ushort*)carve((size_t)N_NODES * FEAT * 2);   // bf16 x
  ushort* wb      = (ushort*)carve((size_t)2 * FEAT * FEAT * 2);  // bf16 conv1/2 W
  ushort* msl     = (ushort*)carve((size_t)N_NODES * FEAT * 2);   // bf16 messages
  ushort* hbuf    = (ushort*)carve((size_t)N_PAD * FEAT * 2);     // bf16 h (padded)
  float*  coefT   = (float*)carve((size_t)NGRAPH * N_PAD * 4);    // fp32, padded
  float*  f_sum   = (float*)carve(NGRAPH * FEAT * 4);             // P
  float*  cnt_g   = (float*)carve(NGRAPH * 4);                    // adjacent to f_sum

  const int BLK_E = (N_EDGES + 255) / 256;
  const int BLK_N = (N_NODES + 255) / 256;

  // zero-init (ws + out are poisoned 0xAA each timed call)
  hipMemsetAsync(cnt_i, 0, N_NODES * 4, stream);
  hipMemsetAsync(coefT, 0, (size_t)NGRAPH * N_PAD * 4, stream);   // pad cols stay 0
  hipMemsetAsync(f_sum, 0, NGRAPH * FEAT * 4 + 256, stream);      // f_sum + cnt_g

  // ---- fp32 -> bf16 prep (x, conv1/2 weights; conv3 stays fp32) ----
  cvt_bf16<<<(N_NODES * FEAT / 4 + 255) / 256, 256, 0, stream>>>(x, xb, N_NODES * FEAT / 4);
  cvt_bf16<<<(FEAT * FEAT / 4 + 255) / 256, 256, 0, stream>>>(conv_w[0], wb,               FEAT * FEAT / 4);
  cvt_bf16<<<(FEAT * FEAT / 4 + 255) / 256, 256, 0, stream>>>(conv_w[1], wb + FEAT * FEAT, FEAT * FEAT / 4);

  // ---- build CSR + norms + coefT (bucketized 2-stage scatter) ----
  count_deg<<<BLK_E, 256, 0, stream>>>(e_dst, cnt_i);
  compute_dinv<<<BLK_N, 256, 0, stream>>>(cnt_i, batch, dinv, coefT, cnt_g);
  scan1<<<BLK_N, 256, 0, stream>>>(cnt_i, csr_ptr, bsums);
  scan2<<<1, 256, 0, stream>>>(bsums, BLK_N);
  scan3<<<BLK_N, 256, 0, stream>>>(csr_ptr, cursor, bsums, bcur);
  scatter_bucket<<<BLK_E, 256, 0, stream>>>(e_src, e_dst, dinv, bcur, tmp);
  csr_scatter<<<BLK_E, 256, 0, stream>>>(tmp, batch, cursor, edges, coefT);

  const int GEMM_BLKS = (N_NODES / 16) * 8 / 4;
  const int AGG_BLKS  = (N_NODES + 3) / 4;
  const int POOL_BLKS = (NCHUNKS * 8 * 4) / 4;   // 784

  // ---- conv1 ----
  gemm128<<<GEMM_BLKS, 256, 0, stream>>>(xb, wb, msl, N_NODES / 16);
  agg_kernel<<<AGG_BLKS, 256, 0, stream>>>(msl, dinv, csr_ptr, cnt_i, edges,
                                           conv_b[0], hbuf);
  // ---- conv2 ----
  gemm128<<<GEMM_BLKS, 256, 0, stream>>>(hbuf, wb + FEAT * FEAT, msl, N_NODES / 16);
  agg_kernel<<<AGG_BLKS, 256, 0, stream>>>(msl, dinv, csr_ptr, cnt_i, edges,
                                           conv_b[1], hbuf);
  // ---- conv3 (algebraic): MFMA pool of h2 (in-register A cvt) ----
  pool_mfma<<<POOL_BLKS, 256, 0, stream>>>(hbuf, coefT, f_sum);

  // ---- fused head: Pn -> W3 -> fc1..fc5 (one launch) ----
  fc_head<<<NGRAPH, 1024, 0, stream>>>(f_sum, cnt_g, conv_w[2], conv_b[2],
                                       fc_w[0], fc_b[0], fc_w[1], fc_b[1],
                                       fc_w[2], fc_b[2], fc_w[3], fc_b[3],
                                       fc_w[4], fc_b[4], out_f, out_y);
}

// Round 15
// 439.907 us; speedup vs baseline: 1.1292x; 1.1292x over previous
//
#include <hip/hip_runtime.h>
#include <stdint.h>

#define N_NODES 50000
#define N_EDGES 800000
#define N_PAD   50176    // 98 * 512, K-padding for MFMA pool
#define FEAT    128
#define NGRAPH  64
#define PCHUNK  512
#define NCHUNKS (N_PAD / PCHUNK)   // 98

typedef __attribute__((ext_vector_type(8))) short short8;
typedef __attribute__((ext_vector_type(4))) float floatx4;

static __device__ __forceinline__ ushort f2bf(float f) {
  uint32_t x = __float_as_uint(f);
  x += 0x7FFF + ((x >> 16) & 1);   // RNE
  return (ushort)(x >> 16);
}
static __device__ __forceinline__ float bfLo(uint32_t u) {
  return __uint_as_float(u << 16);
}
static __device__ __forceinline__ float bfHi(uint32_t u) {
  return __uint_as_float(u & 0xFFFF0000u);
}

// ---------------- fp32 -> bf16 row-major ---------------------------------
__global__ __launch_bounds__(256) void cvt_bf16(const float* __restrict__ in,
                                                ushort* __restrict__ out, int n4) {
  int i = blockIdx.x * 256 + threadIdx.x;
  if (i >= n4) return;
  float4 v = ((const float4*)in)[i];
  ushort4 u;
  u.x = f2bf(v.x); u.y = f2bf(v.y); u.z = f2bf(v.z); u.w = f2bf(v.w);
  ((ushort4*)out)[i] = u;
}

// ---------------- degree count -------------------------------------------
__global__ __launch_bounds__(256) void count_deg(const int* __restrict__ dst,
                                                 int* __restrict__ cnt) {
  int e = blockIdx.x * 256 + threadIdx.x;
  if (e < N_EDGES) atomicAdd(&cnt[dst[e]], 1);
}

// dinv + coef self-term + per-graph node counts (LDS binned)
__global__ __launch_bounds__(256) void compute_dinv(const int* __restrict__ cnt,
                                                    const int* __restrict__ batch,
                                                    float* __restrict__ dinv,
                                                    float* __restrict__ coefT,
                                                    float* __restrict__ cnt_g) {
  __shared__ int bins[NGRAPH];
  if (threadIdx.x < NGRAPH) bins[threadIdx.x] = 0;
  __syncthreads();
  int i = blockIdx.x * 256 + threadIdx.x;
  if (i < N_NODES) {
    float di = rsqrtf((float)cnt[i] + 1.0f);
    dinv[i] = di;
    int g = batch[i];
    coefT[(size_t)g * N_PAD + i] = di * di;   // coalesced (batch sorted)
    atomicAdd(&bins[g], 1);
  }
  __syncthreads();
  if (threadIdx.x < NGRAPH && bins[threadIdx.x] > 0)
    atomicAdd(&cnt_g[threadIdx.x], (float)bins[threadIdx.x]);
}

// ---------------- exclusive scan (3 kernels) -----------------------------
__global__ __launch_bounds__(256) void scan1(const int* __restrict__ cnt,
                                             int* __restrict__ ptr,
                                             int* __restrict__ bsums) {
  __shared__ int tmp[256];
  int i = blockIdx.x * 256 + threadIdx.x;
  int v = (i < N_NODES) ? cnt[i] : 0;
  tmp[threadIdx.x] = v;
  __syncthreads();
  for (int off = 1; off < 256; off <<= 1) {
    int t = (threadIdx.x >= off) ? tmp[threadIdx.x - off] : 0;
    __syncthreads();
    tmp[threadIdx.x] += t;
    __syncthreads();
  }
  if (i < N_NODES) ptr[i] = tmp[threadIdx.x] - v;           // exclusive
  if (threadIdx.x == 255) bsums[blockIdx.x] = tmp[255];
}

__global__ __launch_bounds__(256) void scan2(int* __restrict__ bsums, int nb) {
  __shared__ int tmp[256];
  int v = (threadIdx.x < nb) ? bsums[threadIdx.x] : 0;
  tmp[threadIdx.x] = v;
  __syncthreads();
  for (int off = 1; off < 256; off <<= 1) {
    int t = (threadIdx.x >= off) ? tmp[threadIdx.x - off] : 0;
    __syncthreads();
    tmp[threadIdx.x] += t;
    __syncthreads();
  }
  if (threadIdx.x < nb) bsums[threadIdx.x] = tmp[threadIdx.x] - v;  // exclusive
}

__global__ __launch_bounds__(256) void scan3(int* __restrict__ ptr,
                                             int* __restrict__ cursor,
                                             const int* __restrict__ bsums) {
  int i = blockIdx.x * 256 + threadIdx.x;
  if (i < N_NODES) {
    int p = ptr[i] + bsums[blockIdx.x];
    ptr[i] = p;
    cursor[i] = p;
  }
}

// ---------------- CSR fill + fused coef edge terms -----------------------
// Edge record stored with a non-temporal 8B store: random scatter, never
// re-read until two kernels later -> skip write-allocate residency.
__global__ __launch_bounds__(256) void fill_csr(const int* __restrict__ src,
                                                const int* __restrict__ dst,
                                                const float* __restrict__ dinv,
                                                const int* __restrict__ batch,
                                                int* __restrict__ cursor,
                                                int2* __restrict__ edges,
                                                float* __restrict__ coefT) {
  int e = blockIdx.x * 256 + threadIdx.x;
  if (e >= N_EDGES) return;
  int s = src[e], d = dst[e];
  int pos = atomicAdd(&cursor[d], 1);
  float nrm = dinv[s] * dinv[d];
  uint64_t rec = (uint32_t)s | ((uint64_t)(uint32_t)__float_as_int(nrm) << 32);
  __builtin_nontemporal_store(rec, (uint64_t*)(edges + pos));
  atomicAdd(&coefT[(size_t)batch[d] * N_PAD + s], nrm);
}

// ---------------- GEMM [M,128] x [128,128] via MFMA bf16, bf16 out -------
__global__ __launch_bounds__(256) void gemm128(const ushort* __restrict__ X,
                                               const ushort* __restrict__ W,
                                               ushort* __restrict__ XW,
                                               int nTilesM) {
  int wave = (blockIdx.x * 256 + threadIdx.x) >> 6;
  int lane = threadIdx.x & 63;
  int mt = wave >> 3;  // 8 n-tiles per m-tile
  int nt = wave & 7;
  if (mt >= nTilesM) return;
  int m0 = mt * 16, n0 = nt * 16;
  int r = lane & 15, quad = lane >> 4;
  floatx4 acc = {0.f, 0.f, 0.f, 0.f};
  const ushort* xrow = X + (size_t)(m0 + r) * FEAT;
#pragma unroll
  for (int kb = 0; kb < 4; ++kb) {
    int k0 = kb * 32 + quad * 8;
    short8 a = *(const short8*)(xrow + k0);
    short8 b;
#pragma unroll
    for (int j = 0; j < 8; ++j) b[j] = (short)W[(size_t)(k0 + j) * FEAT + n0 + r];
    acc = __builtin_amdgcn_mfma_f32_16x16x32_bf16(a, b, acc, 0, 0, 0);
  }
#pragma unroll
  for (int reg = 0; reg < 4; ++reg) {
    int row = quad * 4 + reg;
    XW[(size_t)(m0 + row) * FEAT + n0 + r] = f2bf(acc[reg]);
  }
}

// ---------------- aggregation (r6 proven): wave/node, 8-edge ILP ---------
__global__ __launch_bounds__(256) void agg_kernel(const ushort* __restrict__ msg,
                                                  const float* __restrict__ dinv,
                                                  const int* __restrict__ ptr,
                                                  const int* __restrict__ cnt,
                                                  const int2* __restrict__ edges,
                                                  const float* __restrict__ bias,
                                                  ushort* __restrict__ Hout) {
  int wave = (blockIdx.x * 256 + threadIdx.x) >> 6;
  int lane = threadIdx.x & 63;
  if (wave >= N_NODES) return;
  int v = wave;
  float di = dinv[v];
  const uint32_t* m32 = (const uint32_t*)msg;   // 64 dwords per node row
  uint32_t su = m32[(size_t)v * 64 + lane];
  float sn = di * di;
  float ax0 = bfLo(su) * sn, ay0 = bfHi(su) * sn;
  float ax1 = 0.f, ay1 = 0.f, ax2 = 0.f, ay2 = 0.f, ax3 = 0.f, ay3 = 0.f;
  int start = ptr[v];
  int n = cnt[v];
  int i = 0;
  if ((start & 1) && n > 0) {
    int2 e = edges[start];
    uint32_t u = m32[(size_t)e.x * 64 + lane];
    float nrm = __int_as_float(e.y);
    ax0 = fmaf(nrm, bfLo(u), ax0);
    ay0 = fmaf(nrm, bfHi(u), ay0);
    i = 1;
  }
  for (; i + 8 <= n; i += 8) {
    const int4* ep = (const int4*)(edges + start + i);   // 16B-aligned
    int4 q0 = ep[0], q1 = ep[1], q2 = ep[2], q3 = ep[3];
    uint32_t u0 = m32[(size_t)q0.x * 64 + lane];
    uint32_t u1 = m32[(size_t)q0.z * 64 + lane];
    uint32_t u2 = m32[(size_t)q1.x * 64 + lane];
    uint32_t u3 = m32[(size_t)q1.z * 64 + lane];
    uint32_t u4 = m32[(size_t)q2.x * 64 + lane];
    uint32_t u5 = m32[(size_t)q2.z * 64 + lane];
    uint32_t u6 = m32[(size_t)q3.x * 64 + lane];
    uint32_t u7 = m32[(size_t)q3.z * 64 + lane];
    float n0 = __int_as_float(q0.y), n1 = __int_as_float(q0.w);
    float n2 = __int_as_float(q1.y), n3 = __int_as_float(q1.w);
    float n4 = __int_as_float(q2.y), n5 = __int_as_float(q2.w);
    float n6 = __int_as_float(q3.y), n7 = __int_as_float(q3.w);
    ax0 = fmaf(n0, bfLo(u0), ax0); ay0 = fmaf(n0, bfHi(u0), ay0);
    ax1 = fmaf(n1, bfLo(u1), ax1); ay1 = fmaf(n1, bfHi(u1), ay1);
    ax2 = fmaf(n2, bfLo(u2), ax2); ay2 = fmaf(n2, bfHi(u2), ay2);
    ax3 = fmaf(n3, bfLo(u3), ax3); ay3 = fmaf(n3, bfHi(u3), ay3);
    ax0 = fmaf(n4, bfLo(u4), ax0); ay0 = fmaf(n4, bfHi(u4), ay0);
    ax1 = fmaf(n5, bfLo(u5), ax1); ay1 = fmaf(n5, bfHi(u5), ay1);
    ax2 = fmaf(n6, bfLo(u6), ax2); ay2 = fmaf(n6, bfHi(u6), ay2);
    ax3 = fmaf(n7, bfLo(u7), ax3); ay3 = fmaf(n7, bfHi(u7), ay3);
  }
  for (; i < n; ++i) {
    int2 e = edges[start + i];
    float nrm = __int_as_float(e.y);
    uint32_t u = m32[(size_t)e.x * 64 + lane];
    ax0 = fmaf(nrm, bfLo(u), ax0);
    ay0 = fmaf(nrm, bfHi(u), ay0);
  }
  float ax = (ax0 + ax1) + (ax2 + ax3) + bias[2 * lane];
  float ay = (ay0 + ay1) + (ay2 + ay3) + bias[2 * lane + 1];
  ax = fmaxf(ax, 0.f);
  ay = fmaxf(ay, 0.f);
  ushort2 h2;
  h2.x = f2bf(ax);
  h2.y = f2bf(ay);
  ((ushort2*)Hout)[(size_t)v * 64 + lane] = h2;
}

// ---------------- pool v4: P = coefT x h2 via MFMA (in-reg bf16 cvt) -----
__global__ __launch_bounds__(256) void pool_mfma(const ushort* __restrict__ h2,
                                                 const float* __restrict__ coefT,
                                                 float* __restrict__ P) {
  int wave = (blockIdx.x * 256 + threadIdx.x) >> 6;
  int lane = threadIdx.x & 63;
  int mt = wave & 3;
  int nt = (wave >> 2) & 7;
  int ck = wave >> 5;
  if (ck >= NCHUNKS) return;
  int c0 = ck * PCHUNK;
  int m0 = mt * 16, n0 = nt * 16;
  int r = lane & 15, quad = lane >> 4;
  floatx4 acc = {0.f, 0.f, 0.f, 0.f};
  const float* arow = coefT + (size_t)(m0 + r) * N_PAD + c0;
#pragma unroll 4
  for (int kb = 0; kb < 16; ++kb) {
    int k0 = kb * 32 + quad * 8;
    float4 af0 = *(const float4*)(arow + k0);
    float4 af1 = *(const float4*)(arow + k0 + 4);
    short8 a;
    a[0] = (short)f2bf(af0.x); a[1] = (short)f2bf(af0.y);
    a[2] = (short)f2bf(af0.z); a[3] = (short)f2bf(af0.w);
    a[4] = (short)f2bf(af1.x); a[5] = (short)f2bf(af1.y);
    a[6] = (short)f2bf(af1.z); a[7] = (short)f2bf(af1.w);
    short8 b;
#pragma unroll
    for (int j = 0; j < 8; ++j)
      b[j] = (short)h2[(size_t)(c0 + k0 + j) * FEAT + n0 + r];
    acc = __builtin_amdgcn_mfma_f32_16x16x32_bf16(a, b, acc, 0, 0, 0);
  }
#pragma unroll
  for (int reg = 0; reg < 4; ++reg) {
    int row = quad * 4 + reg;                    // graph within m-tile
    atomicAdd(&P[(size_t)(m0 + row) * FEAT + n0 + r], acc[reg]);
  }
}

// ---------------- fused head: Pn = P/cnt; f = Pn*W3+b3; fc1..fc5 ---------
__device__ __forceinline__ void head_layer(const float* __restrict__ IN,
                                           float* __restrict__ OUT,
                                           const float* __restrict__ w,
                                           const float* __restrict__ b,
                                           int K, int C, int Cp, int relu,
                                           float* __restrict__ gout, int t) {
  int parts = 1024 / Cp;
  int part = t / Cp;
  int c = t - part * Cp;
  int kchunk = K / parts;
  if (t < C) OUT[t] = b[t];
  __syncthreads();
  if (c < C) {
    int k0 = part * kchunk;
    float a0 = 0.f, a1 = 0.f, a2 = 0.f, a3 = 0.f;
    const float* wp = w + (size_t)k0 * C + c;
    if ((kchunk & 3) == 0) {
#pragma unroll 4
      for (int k = 0; k < kchunk; k += 4) {
        a0 = fmaf(IN[k0 + k],     wp[(size_t)k * C],       a0);
        a1 = fmaf(IN[k0 + k + 1], wp[(size_t)(k + 1) * C], a1);
        a2 = fmaf(IN[k0 + k + 2], wp[(size_t)(k + 2) * C], a2);
        a3 = fmaf(IN[k0 + k + 3], wp[(size_t)(k + 3) * C], a3);
      }
    } else {
      for (int k = 0; k < kchunk; ++k)
        a0 = fmaf(IN[k0 + k], wp[(size_t)k * C], a0);
    }
    atomicAdd(&OUT[c], (a0 + a1) + (a2 + a3));
  }
  __syncthreads();
  if (t < C) {
    float v = OUT[t];
    if (relu) { v = fmaxf(v, 0.f); OUT[t] = v; }
    if (gout) gout[t] = v;
  }
  __syncthreads();
}

__global__ __launch_bounds__(1024) void fc_head(const float* __restrict__ P,
                                                const float* __restrict__ cnt_g,
                                                const float* __restrict__ w3,
                                                const float* __restrict__ b3,
                                                const float* __restrict__ w1,
                                                const float* __restrict__ b1,
                                                const float* __restrict__ w2,
                                                const float* __restrict__ b2,
                                                const float* __restrict__ wf3,
                                                const float* __restrict__ bf3,
                                                const float* __restrict__ w4,
                                                const float* __restrict__ b4,
                                                const float* __restrict__ w5,
                                                const float* __restrict__ b5,
                                                float* __restrict__ out_f,
                                                float* __restrict__ out_y) {
  __shared__ float A[1024];
  __shared__ float B[1024];
  int r = blockIdx.x, t = threadIdx.x;
  if (t < FEAT) A[t] = P[r * FEAT + t] / fmaxf(cnt_g[r], 1.0f);   // Pn
  __syncthreads();
  head_layer(A, B, w3, b3, 128, 128, 128, 0, out_f + (size_t)r * FEAT, t);
  head_layer(B, A, w1, b1, 128, 1024, 1024, 1, nullptr, t);
  head_layer(A, B, w2, b2, 1024, 512, 512, 1, nullptr, t);
  head_layer(B, A, wf3, bf3, 512, 256, 256, 1, nullptr, t);
  head_layer(A, B, w4, b4, 256, 128, 128, 1, nullptr, t);
  head_layer(B, A, w5, b5, 128, 10, 16, 0, out_y + (size_t)r * 10, t);
}

// =========================================================================
extern "C" void kernel_launch(void* const* d_in, const int* in_sizes, int n_in,
                              void* d_out, int out_size, void* d_ws, size_t ws_size,
                              hipStream_t stream) {
  const float* x         = (const float*)d_in[0];
  const int*   ei        = (const int*)d_in[1];     // [2][E]: row0 src, row1 dst
  const int*   batch     = (const int*)d_in[2];
  const float* conv_w[3] = {(const float*)d_in[3], (const float*)d_in[5], (const float*)d_in[7]};
  const float* conv_b[3] = {(const float*)d_in[4], (const float*)d_in[6], (const float*)d_in[8]};
  const float* fc_w[5]   = {(const float*)d_in[9],  (const float*)d_in[11],
                            (const float*)d_in[13], (const float*)d_in[15],
                            (const float*)d_in[17]};
  const float* fc_b[5]   = {(const float*)d_in[10], (const float*)d_in[12],
                            (const float*)d_in[14], (const float*)d_in[16],
                            (const float*)d_in[18]};
  const int* e_src = ei;
  const int* e_dst = ei + N_EDGES;
  float* out_f = (float*)d_out;                  // [64][128] fp32  (output 0)
  float* out_y = (float*)d_out + NGRAPH * FEAT;  // [64][10]  fp32  (output 1)

  char* p = (char*)d_ws;
  auto carve = [&](size_t bytes) {
    char* r = p;
    p += (bytes + 255) & ~(size_t)255;
    return r;
  };
  int*    cnt_i   = (int*)carve(N_NODES * 4);
  float*  dinv    = (float*)carve(N_NODES * 4);
  int*    csr_ptr = (int*)carve(N_NODES * 4);
  int*    cursor  = (int*)carve(N_NODES * 4);
  int*    bsums   = (int*)carve(256 * 4);
  int2*   edges   = (int2*)carve((size_t)N_EDGES * 8);
  ushort* xb      = (ushort*)carve((size_t)N_NODES * FEAT * 2);   // bf16 x
  ushort* wb      = (ushort*)carve((size_t)2 * FEAT * FEAT * 2);  // bf16 conv1/2 W
  ushort* msl     = (ushort*)carve((size_t)N_NODES * FEAT * 2);   // bf16 messages
  ushort* hbuf    = (ushort*)carve((size_t)N_PAD * FEAT * 2);     // bf16 h (padded)
  float*  coefT   = (float*)carve((size_t)NGRAPH * N_PAD * 4);    // fp32, padded
  float*  f_sum   = (float*)carve(NGRAPH * FEAT * 4);             // P
  float*  cnt_g   = (float*)carve(NGRAPH * 4);                    // adjacent to f_sum

  const int BLK_E = (N_EDGES + 255) / 256;
  const int BLK_N = (N_NODES + 255) / 256;

  // zero-init (ws + out are poisoned 0xAA each timed call)
  hipMemsetAsync(cnt_i, 0, N_NODES * 4, stream);
  hipMemsetAsync(coefT, 0, (size_t)NGRAPH * N_PAD * 4, stream);   // pad cols stay 0
  hipMemsetAsync(f_sum, 0, NGRAPH * FEAT * 4 + 256, stream);      // f_sum + cnt_g

  // ---- fp32 -> bf16 prep (x, conv1/2 weights; conv3 stays fp32) ----
  cvt_bf16<<<(N_NODES * FEAT / 4 + 255) / 256, 256, 0, stream>>>(x, xb, N_NODES * FEAT / 4);
  cvt_bf16<<<(FEAT * FEAT / 4 + 255) / 256, 256, 0, stream>>>(conv_w[0], wb,               FEAT * FEAT / 4);
  cvt_bf16<<<(FEAT * FEAT / 4 + 255) / 256, 256, 0, stream>>>(conv_w[1], wb + FEAT * FEAT, FEAT * FEAT / 4);

  // ---- build CSR + norms + coefT (edge terms fused into fill) ----
  count_deg<<<BLK_E, 256, 0, stream>>>(e_dst, cnt_i);
  compute_dinv<<<BLK_N, 256, 0, stream>>>(cnt_i, batch, dinv, coefT, cnt_g);
  scan1<<<BLK_N, 256, 0, stream>>>(cnt_i, csr_ptr, bsums);
  scan2<<<1, 256, 0, stream>>>(bsums, BLK_N);
  scan3<<<BLK_N, 256, 0, stream>>>(csr_ptr, cursor, bsums);
  fill_csr<<<BLK_E, 256, 0, stream>>>(e_src, e_dst, dinv, batch, cursor, edges, coefT);

  const int GEMM_BLKS = (N_NODES / 16) * 8 / 4;
  const int AGG_BLKS  = (N_NODES + 3) / 4;
  const int POOL_BLKS = (NCHUNKS * 8 * 4) / 4;   // 784

  // ---- conv1 ----
  gemm128<<<GEMM_BLKS, 256, 0, stream>>>(xb, wb, msl, N_NODES / 16);
  agg_kernel<<<AGG_BLKS, 256, 0, stream>>>(msl, dinv, csr_ptr, cnt_i, edges,
                                           conv_b[0], hbuf);
  // ---- conv2 ----
  gemm128<<<GEMM_BLKS, 256, 0, stream>>>(hbuf, wb + FEAT * FEAT, msl, N_NODES / 16);
  agg_kernel<<<AGG_BLKS, 256, 0, stream>>>(msl, dinv, csr_ptr, cnt_i, edges,
                                           conv_b[1], hbuf);
  // ---- conv3 (algebraic): MFMA pool of h2 (in-register A cvt) ----
  pool_mfma<<<POOL_BLKS, 256, 0, stream>>>(hbuf, coefT, f_sum);

  // ---- fused head: Pn -> W3 -> fc1..fc5 (one launch) ----
  fc_head<<<NGRAPH, 1024, 0, stream>>>(f_sum, cnt_g, conv_w[2], conv_b[2],
                                       fc_w[0], fc_b[0], fc_w[1], fc_b[1],
                                       fc_w[2], fc_b[2], fc_w[3], fc_b[3],
                                       fc_w[4], fc_b[4], out_f, out_y);
}

// Round 16
// 421.053 us; speedup vs baseline: 1.1798x; 1.0448x over previous
//
#include <hip/hip_runtime.h>
#include <stdint.h>

#define N_NODES 50000
#define N_EDGES 800000
#define N_PAD   50176    // 98 * 512, K-padding for MFMA pool
#define FEAT    128
#define NGRAPH  64
#define PCHUNK  512
#define NCHUNKS (N_PAD / PCHUNK)   // 98

#define XB_BLKS   6250   // x cvt: 1.6M float4 / 256
#define W_BLKS    32     // two 128x128 weight cvts
#define CZ_BLKS   3136   // coefT zero: 802816 float4 / 256
#define E_BLKS    3125   // 800000 edges / 256
#define GEMM_BLKS 6250   // (N/16) m-tiles * 8 n-tiles / 4 waves

typedef __attribute__((ext_vector_type(8))) short short8;
typedef __attribute__((ext_vector_type(4))) float floatx4;

static __device__ __forceinline__ ushort f2bf(float f) {
  uint32_t x = __float_as_uint(f);
  x += 0x7FFF + ((x >> 16) & 1);   // RNE
  return (ushort)(x >> 16);
}
static __device__ __forceinline__ float bfLo(uint32_t u) {
  return __uint_as_float(u << 16);
}
static __device__ __forceinline__ float bfHi(uint32_t u) {
  return __uint_as_float(u & 0xFFFF0000u);
}

static __device__ __forceinline__ void cvt4(const float* __restrict__ in,
                                            ushort* __restrict__ out, int i) {
  float4 v = ((const float4*)in)[i];
  ushort4 u;
  u.x = f2bf(v.x); u.y = f2bf(v.y); u.z = f2bf(v.z); u.w = f2bf(v.w);
  ((ushort4*)out)[i] = u;
}

// ---- fused prep: cvt x, cvt w1/w2, zero coefT, count_deg (independent) ---
__global__ __launch_bounds__(256) void prep_fused(const float* __restrict__ x,
                                                  ushort* __restrict__ xb,
                                                  const float* __restrict__ w0,
                                                  const float* __restrict__ w1,
                                                  ushort* __restrict__ wb,
                                                  float* __restrict__ coefT,
                                                  const int* __restrict__ dst,
                                                  int* __restrict__ cnt) {
  int b = blockIdx.x, t = threadIdx.x;
  if (b < XB_BLKS) {
    cvt4(x, xb, b * 256 + t);
  } else if (b < XB_BLKS + W_BLKS) {
    int i = (b - XB_BLKS) * 256 + t;           // 0..8191 over two weights
    if (i < 4096) cvt4(w0, wb, i);
    else cvt4(w1, wb + FEAT * FEAT, i - 4096);
  } else if (b < XB_BLKS + W_BLKS + CZ_BLKS) {
    int i = (b - XB_BLKS - W_BLKS) * 256 + t;
    if (i < NGRAPH * N_PAD / 4)
      ((float4*)coefT)[i] = make_float4(0.f, 0.f, 0.f, 0.f);
  } else {
    int e = (b - XB_BLKS - W_BLKS - CZ_BLKS) * 256 + t;
    if (e < N_EDGES) atomicAdd(&cnt[dst[e]], 1);
  }
}

// ---- fused: dinv + coef self-term + graph counts + scan1 (all read cnt) --
__global__ __launch_bounds__(256) void dinv_scan1(const int* __restrict__ cnt,
                                                  const int* __restrict__ batch,
                                                  float* __restrict__ dinv,
                                                  float* __restrict__ coefT,
                                                  float* __restrict__ cnt_g,
                                                  int* __restrict__ ptr,
                                                  int* __restrict__ bsums) {
  __shared__ int tmp[256];
  __shared__ int bins[NGRAPH];
  if (threadIdx.x < NGRAPH) bins[threadIdx.x] = 0;
  int i = blockIdx.x * 256 + threadIdx.x;
  int v = (i < N_NODES) ? cnt[i] : 0;
  tmp[threadIdx.x] = v;
  __syncthreads();
  for (int off = 1; off < 256; off <<= 1) {
    int t = (threadIdx.x >= off) ? tmp[threadIdx.x - off] : 0;
    __syncthreads();
    tmp[threadIdx.x] += t;
    __syncthreads();
  }
  if (i < N_NODES) ptr[i] = tmp[threadIdx.x] - v;           // exclusive
  if (threadIdx.x == 255) bsums[blockIdx.x] = tmp[255];
  if (i < N_NODES) {
    float di = rsqrtf((float)v + 1.0f);
    dinv[i] = di;
    int g = batch[i];
    coefT[(size_t)g * N_PAD + i] = di * di;   // coalesced (batch sorted)
    atomicAdd(&bins[g], 1);
  }
  __syncthreads();
  if (threadIdx.x < NGRAPH && bins[threadIdx.x] > 0)
    atomicAdd(&cnt_g[threadIdx.x], (float)bins[threadIdx.x]);
}

__global__ __launch_bounds__(256) void scan2(int* __restrict__ bsums, int nb) {
  __shared__ int tmp[256];
  int v = (threadIdx.x < nb) ? bsums[threadIdx.x] : 0;
  tmp[threadIdx.x] = v;
  __syncthreads();
  for (int off = 1; off < 256; off <<= 1) {
    int t = (threadIdx.x >= off) ? tmp[threadIdx.x - off] : 0;
    __syncthreads();
    tmp[threadIdx.x] += t;
    __syncthreads();
  }
  if (threadIdx.x < nb) bsums[threadIdx.x] = tmp[threadIdx.x] - v;  // exclusive
}

__global__ __launch_bounds__(256) void scan3(int* __restrict__ ptr,
                                             int* __restrict__ cursor,
                                             const int* __restrict__ bsums) {
  int i = blockIdx.x * 256 + threadIdx.x;
  if (i < N_NODES) {
    int p = ptr[i] + bsums[blockIdx.x];
    ptr[i] = p;
    cursor[i] = p;
  }
}

// ---- shared gemm body: [M,128] x [128,128] MFMA bf16, bf16 out ----------
static __device__ __forceinline__ void gemm_body(int wave, int lane,
                                                 const ushort* __restrict__ X,
                                                 const ushort* __restrict__ W,
                                                 ushort* __restrict__ XW) {
  int mt = wave >> 3;  // 8 n-tiles per m-tile
  int nt = wave & 7;
  if (mt >= N_NODES / 16) return;
  int m0 = mt * 16, n0 = nt * 16;
  int r = lane & 15, quad = lane >> 4;
  floatx4 acc = {0.f, 0.f, 0.f, 0.f};
  const ushort* xrow = X + (size_t)(m0 + r) * FEAT;
#pragma unroll
  for (int kb = 0; kb < 4; ++kb) {
    int k0 = kb * 32 + quad * 8;
    short8 a = *(const short8*)(xrow + k0);
    short8 b;
#pragma unroll
    for (int j = 0; j < 8; ++j) b[j] = (short)W[(size_t)(k0 + j) * FEAT + n0 + r];
    acc = __builtin_amdgcn_mfma_f32_16x16x32_bf16(a, b, acc, 0, 0, 0);
  }
#pragma unroll
  for (int reg = 0; reg < 4; ++reg) {
    int row = quad * 4 + reg;
    XW[(size_t)(m0 + row) * FEAT + n0 + r] = f2bf(acc[reg]);
  }
}

__global__ __launch_bounds__(256) void gemm128(const ushort* __restrict__ X,
                                               const ushort* __restrict__ W,
                                               ushort* __restrict__ XW) {
  gemm_body((blockIdx.x * 256 + threadIdx.x) >> 6, threadIdx.x & 63, X, W, XW);
}

// ---- fused: conv1 gemm (MFMA-bound) + fill_csr (scatter-bound) ----------
__global__ __launch_bounds__(256) void fill_gemm1(const ushort* __restrict__ X,
                                                  const ushort* __restrict__ W,
                                                  ushort* __restrict__ XW,
                                                  const int* __restrict__ src,
                                                  const int* __restrict__ dst,
                                                  const float* __restrict__ dinv,
                                                  const int* __restrict__ batch,
                                                  int* __restrict__ cursor,
                                                  int2* __restrict__ edges,
                                                  float* __restrict__ coefT) {
  if (blockIdx.x < GEMM_BLKS) {
    gemm_body((blockIdx.x * 256 + threadIdx.x) >> 6, threadIdx.x & 63, X, W, XW);
  } else {
    int e = (blockIdx.x - GEMM_BLKS) * 256 + threadIdx.x;
    if (e >= N_EDGES) return;
    int s = src[e], d = dst[e];
    int pos = atomicAdd(&cursor[d], 1);
    float nrm = dinv[s] * dinv[d];
    edges[pos] = make_int2(s, __float_as_int(nrm));
    atomicAdd(&coefT[(size_t)batch[d] * N_PAD + s], nrm);
  }
}

// ---------------- aggregation (r6 proven): wave/node, 8-edge ILP ---------
__global__ __launch_bounds__(256) void agg_kernel(const ushort* __restrict__ msg,
                                                  const float* __restrict__ dinv,
                                                  const int* __restrict__ ptr,
                                                  const int* __restrict__ cnt,
                                                  const int2* __restrict__ edges,
                                                  const float* __restrict__ bias,
                                                  ushort* __restrict__ Hout) {
  int wave = (blockIdx.x * 256 + threadIdx.x) >> 6;
  int lane = threadIdx.x & 63;
  if (wave >= N_NODES) return;
  int v = wave;
  float di = dinv[v];
  const uint32_t* m32 = (const uint32_t*)msg;   // 64 dwords per node row
  uint32_t su = m32[(size_t)v * 64 + lane];
  float sn = di * di;
  float ax0 = bfLo(su) * sn, ay0 = bfHi(su) * sn;
  float ax1 = 0.f, ay1 = 0.f, ax2 = 0.f, ay2 = 0.f, ax3 = 0.f, ay3 = 0.f;
  int start = ptr[v];
  int n = cnt[v];
  int i = 0;
  if ((start & 1) && n > 0) {
    int2 e = edges[start];
    uint32_t u = m32[(size_t)e.x * 64 + lane];
    float nrm = __int_as_float(e.y);
    ax0 = fmaf(nrm, bfLo(u), ax0);
    ay0 = fmaf(nrm, bfHi(u), ay0);
    i = 1;
  }
  for (; i + 8 <= n; i += 8) {
    const int4* ep = (const int4*)(edges + start + i);   // 16B-aligned
    int4 q0 = ep[0], q1 = ep[1], q2 = ep[2], q3 = ep[3];
    uint32_t u0 = m32[(size_t)q0.x * 64 + lane];
    uint32_t u1 = m32[(size_t)q0.z * 64 + lane];
    uint32_t u2 = m32[(size_t)q1.x * 64 + lane];
    uint32_t u3 = m32[(size_t)q1.z * 64 + lane];
    uint32_t u4 = m32[(size_t)q2.x * 64 + lane];
    uint32_t u5 = m32[(size_t)q2.z * 64 + lane];
    uint32_t u6 = m32[(size_t)q3.x * 64 + lane];
    uint32_t u7 = m32[(size_t)q3.z * 64 + lane];
    float n0 = __int_as_float(q0.y), n1 = __int_as_float(q0.w);
    float n2 = __int_as_float(q1.y), n3 = __int_as_float(q1.w);
    float n4 = __int_as_float(q2.y), n5 = __int_as_float(q2.w);
    float n6 = __int_as_float(q3.y), n7 = __int_as_float(q3.w);
    ax0 = fmaf(n0, bfLo(u0), ax0); ay0 = fmaf(n0, bfHi(u0), ay0);
    ax1 = fmaf(n1, bfLo(u1), ax1); ay1 = fmaf(n1, bfHi(u1), ay1);
    ax2 = fmaf(n2, bfLo(u2), ax2); ay2 = fmaf(n2, bfHi(u2), ay2);
    ax3 = fmaf(n3, bfLo(u3), ax3); ay3 = fmaf(n3, bfHi(u3), ay3);
    ax0 = fmaf(n4, bfLo(u4), ax0); ay0 = fmaf(n4, bfHi(u4), ay0);
    ax1 = fmaf(n5, bfLo(u5), ax1); ay1 = fmaf(n5, bfHi(u5), ay1);
    ax2 = fmaf(n6, bfLo(u6), ax2); ay2 = fmaf(n6, bfHi(u6), ay2);
    ax3 = fmaf(n7, bfLo(u7), ax3); ay3 = fmaf(n7, bfHi(u7), ay3);
  }
  for (; i < n; ++i) {
    int2 e = edges[start + i];
    float nrm = __int_as_float(e.y);
    uint32_t u = m32[(size_t)e.x * 64 + lane];
    ax0 = fmaf(nrm, bfLo(u), ax0);
    ay0 = fmaf(nrm, bfHi(u), ay0);
  }
  float ax = (ax0 + ax1) + (ax2 + ax3) + bias[2 * lane];
  float ay = (ay0 + ay1) + (ay2 + ay3) + bias[2 * lane + 1];
  ax = fmaxf(ax, 0.f);
  ay = fmaxf(ay, 0.f);
  ushort2 h2;
  h2.x = f2bf(ax);
  h2.y = f2bf(ay);
  ((ushort2*)Hout)[(size_t)v * 64 + lane] = h2;
}

// ---------------- pool v4: P = coefT x h2 via MFMA (in-reg bf16 cvt) -----
__global__ __launch_bounds__(256) void pool_mfma(const ushort* __restrict__ h2,
                                                 const float* __restrict__ coefT,
                                                 float* __restrict__ P) {
  int wave = (blockIdx.x * 256 + threadIdx.x) >> 6;
  int lane = threadIdx.x & 63;
  int mt = wave & 3;
  int nt = (wave >> 2) & 7;
  int ck = wave >> 5;
  if (ck >= NCHUNKS) return;
  int c0 = ck * PCHUNK;
  int m0 = mt * 16, n0 = nt * 16;
  int r = lane & 15, quad = lane >> 4;
  floatx4 acc = {0.f, 0.f, 0.f, 0.f};
  const float* arow = coefT + (size_t)(m0 + r) * N_PAD + c0;
#pragma unroll 4
  for (int kb = 0; kb < 16; ++kb) {
    int k0 = kb * 32 + quad * 8;
    float4 af0 = *(const float4*)(arow + k0);
    float4 af1 = *(const float4*)(arow + k0 + 4);
    short8 a;
    a[0] = (short)f2bf(af0.x); a[1] = (short)f2bf(af0.y);
    a[2] = (short)f2bf(af0.z); a[3] = (short)f2bf(af0.w);
    a[4] = (short)f2bf(af1.x); a[5] = (short)f2bf(af1.y);
    a[6] = (short)f2bf(af1.z); a[7] = (short)f2bf(af1.w);
    short8 b;
#pragma unroll
    for (int j = 0; j < 8; ++j)
      b[j] = (short)h2[(size_t)(c0 + k0 + j) * FEAT + n0 + r];
    acc = __builtin_amdgcn_mfma_f32_16x16x32_bf16(a, b, acc, 0, 0, 0);
  }
#pragma unroll
  for (int reg = 0; reg < 4; ++reg) {
    int row = quad * 4 + reg;                    // graph within m-tile
    atomicAdd(&P[(size_t)(m0 + row) * FEAT + n0 + r], acc[reg]);
  }
}

// ---------------- fused head: Pn = P/cnt; f = Pn*W3+b3; fc1..fc5 ---------
__device__ __forceinline__ void head_layer(const float* __restrict__ IN,
                                           float* __restrict__ OUT,
                                           const float* __restrict__ w,
                                           const float* __restrict__ b,
                                           int K, int C, int Cp, int relu,
                                           float* __restrict__ gout, int t) {
  int parts = 1024 / Cp;
  int part = t / Cp;
  int c = t - part * Cp;
  int kchunk = K / parts;
  if (t < C) OUT[t] = b[t];
  __syncthreads();
  if (c < C) {
    int k0 = part * kchunk;
    float a0 = 0.f, a1 = 0.f, a2 = 0.f, a3 = 0.f;
    const float* wp = w + (size_t)k0 * C + c;
    if ((kchunk & 3) == 0) {
#pragma unroll 4
      for (int k = 0; k < kchunk; k += 4) {
        a0 = fmaf(IN[k0 + k],     wp[(size_t)k * C],       a0);
        a1 = fmaf(IN[k0 + k + 1], wp[(size_t)(k + 1) * C], a1);
        a2 = fmaf(IN[k0 + k + 2], wp[(size_t)(k + 2) * C], a2);
        a3 = fmaf(IN[k0 + k + 3], wp[(size_t)(k + 3) * C], a3);
      }
    } else {
      for (int k = 0; k < kchunk; ++k)
        a0 = fmaf(IN[k0 + k], wp[(size_t)k * C], a0);
    }
    atomicAdd(&OUT[c], (a0 + a1) + (a2 + a3));
  }
  __syncthreads();
  if (t < C) {
    float v = OUT[t];
    if (relu) { v = fmaxf(v, 0.f); OUT[t] = v; }
    if (gout) gout[t] = v;
  }
  __syncthreads();
}

__global__ __launch_bounds__(1024) void fc_head(const float* __restrict__ P,
                                                const float* __restrict__ cnt_g,
                                                const float* __restrict__ w3,
                                                const float* __restrict__ b3,
                                                const float* __restrict__ w1,
                                                const float* __restrict__ b1,
                                                const float* __restrict__ w2,
                                                const float* __restrict__ b2,
                                                const float* __restrict__ wf3,
                                                const float* __restrict__ bf3,
                                                const float* __restrict__ w4,
                                                const float* __restrict__ b4,
                                                const float* __restrict__ w5,
                                                const float* __restrict__ b5,
                                                float* __restrict__ out_f,
                                                float* __restrict__ out_y) {
  __shared__ float A[1024];
  __shared__ float B[1024];
  int r = blockIdx.x, t = threadIdx.x;
  if (t < FEAT) A[t] = P[r * FEAT + t] / fmaxf(cnt_g[r], 1.0f);   // Pn
  __syncthreads();
  head_layer(A, B, w3, b3, 128, 128, 128, 0, out_f + (size_t)r * FEAT, t);
  head_layer(B, A, w1, b1, 128, 1024, 1024, 1, nullptr, t);
  head_layer(A, B, w2, b2, 1024, 512, 512, 1, nullptr, t);
  head_layer(B, A, wf3, bf3, 512, 256, 256, 1, nullptr, t);
  head_layer(A, B, w4, b4, 256, 128, 128, 1, nullptr, t);
  head_layer(B, A, w5, b5, 128, 10, 16, 0, out_y + (size_t)r * 10, t);
}

// =========================================================================
extern "C" void kernel_launch(void* const* d_in, const int* in_sizes, int n_in,
                              void* d_out, int out_size, void* d_ws, size_t ws_size,
                              hipStream_t stream) {
  const float* x         = (const float*)d_in[0];
  const int*   ei        = (const int*)d_in[1];     // [2][E]: row0 src, row1 dst
  const int*   batch     = (const int*)d_in[2];
  const float* conv_w[3] = {(const float*)d_in[3], (const float*)d_in[5], (const float*)d_in[7]};
  const float* conv_b[3] = {(const float*)d_in[4], (const float*)d_in[6], (const float*)d_in[8]};
  const float* fc_w[5]   = {(const float*)d_in[9],  (const float*)d_in[11],
                            (const float*)d_in[13], (const float*)d_in[15],
                            (const float*)d_in[17]};
  const float* fc_b[5]   = {(const float*)d_in[10], (const float*)d_in[12],
                            (const float*)d_in[14], (const float*)d_in[16],
                            (const float*)d_in[18]};
  const int* e_src = ei;
  const int* e_dst = ei + N_EDGES;
  float* out_f = (float*)d_out;                  // [64][128] fp32  (output 0)
  float* out_y = (float*)d_out + NGRAPH * FEAT;  // [64][10]  fp32  (output 1)

  char* p = (char*)d_ws;
  auto carve = [&](size_t bytes) {
    char* r = p;
    p += (bytes + 255) & ~(size_t)255;
    return r;
  };
  int*    cnt_i   = (int*)carve(N_NODES * 4);
  float*  dinv    = (float*)carve(N_NODES * 4);
  int*    csr_ptr = (int*)carve(N_NODES * 4);
  int*    cursor  = (int*)carve(N_NODES * 4);
  int*    bsums   = (int*)carve(256 * 4);
  int2*   edges   = (int2*)carve((size_t)N_EDGES * 8);
  ushort* xb      = (ushort*)carve((size_t)N_NODES * FEAT * 2);   // bf16 x
  ushort* wb      = (ushort*)carve((size_t)2 * FEAT * FEAT * 2);  // bf16 conv1/2 W
  ushort* msl     = (ushort*)carve((size_t)N_NODES * FEAT * 2);   // bf16 messages
  ushort* hbuf    = (ushort*)carve((size_t)N_PAD * FEAT * 2);     // bf16 h (padded)
  float*  coefT   = (float*)carve((size_t)NGRAPH * N_PAD * 4);    // fp32, padded
  float*  f_sum   = (float*)carve(NGRAPH * FEAT * 4);             // P
  float*  cnt_g   = (float*)carve(NGRAPH * 4);                    // adjacent to f_sum

  const int BLK_N = (N_NODES + 255) / 256;   // 196

  // zero-init (ws + out are poisoned 0xAA each timed call)
  hipMemsetAsync(cnt_i, 0, N_NODES * 4, stream);
  hipMemsetAsync(f_sum, 0, NGRAPH * FEAT * 4 + 256, stream);      // f_sum + cnt_g

  // ---- fused prep: cvt x/w1/w2 + zero coefT + count_deg (1 dispatch) ----
  prep_fused<<<XB_BLKS + W_BLKS + CZ_BLKS + E_BLKS, 256, 0, stream>>>(
      x, xb, conv_w[0], conv_w[1], wb, coefT, e_dst, cnt_i);

  // ---- dinv + coef self-term + graph counts + scan1 (1 dispatch) ----
  dinv_scan1<<<BLK_N, 256, 0, stream>>>(cnt_i, batch, dinv, coefT, cnt_g,
                                        csr_ptr, bsums);
  scan2<<<1, 256, 0, stream>>>(bsums, BLK_N);
  scan3<<<BLK_N, 256, 0, stream>>>(csr_ptr, cursor, bsums);

  // ---- conv1 gemm co-scheduled with fill_csr (1 dispatch) ----
  fill_gemm1<<<GEMM_BLKS + E_BLKS, 256, 0, stream>>>(
      xb, wb, msl, e_src, e_dst, dinv, batch, cursor, edges, coefT);

  const int AGG_BLKS  = (N_NODES + 3) / 4;
  const int POOL_BLKS = (NCHUNKS * 8 * 4) / 4;   // 784

  // ---- conv1 agg ----
  agg_kernel<<<AGG_BLKS, 256, 0, stream>>>(msl, dinv, csr_ptr, cnt_i, edges,
                                           conv_b[0], hbuf);
  // ---- conv2 ----
  gemm128<<<GEMM_BLKS, 256, 0, stream>>>(hbuf, wb + FEAT * FEAT, msl);
  agg_kernel<<<AGG_BLKS, 256, 0, stream>>>(msl, dinv, csr_ptr, cnt_i, edges,
                                           conv_b[1], hbuf);
  // ---- conv3 (algebraic): MFMA pool of h2 ----
  pool_mfma<<<POOL_BLKS, 256, 0, stream>>>(hbuf, coefT, f_sum);

  // ---- fused head: Pn -> W3 -> fc1..fc5 (one launch) ----
  fc_head<<<NGRAPH, 1024, 0, stream>>>(f_sum, cnt_g, conv_w[2], conv_b[2],
                                       fc_w[0], fc_b[0], fc_w[1], fc_b[1],
                                       fc_w[2], fc_b[2], fc_w[3], fc_b[3],
                                       fc_w[4], fc_b[4], out_f, out_y);
}